// Round 13
// baseline (279.184 us; speedup 1.0000x reference)
//
#include <hip/hip_runtime.h>

#define FEAT 128

typedef __attribute__((ext_vector_type(8))) short short8;
typedef __attribute__((ext_vector_type(4))) float floatx4;

// bf16 helpers (manual, RNE) — finite data only.
__device__ __forceinline__ unsigned short f2bf(float f) {
    unsigned int u = __float_as_uint(f);
    u += 0x7fffu + ((u >> 16) & 1u);
    return (unsigned short)(u >> 16);
}
__device__ __forceinline__ float bf_lo(unsigned int u) { return __uint_as_float(u << 16); }
__device__ __forceinline__ float bf_hi(unsigned int u) { return __uint_as_float(u & 0xffff0000u); }
__device__ __forceinline__ unsigned int pack2(float a, float b) {
    return (unsigned int)f2bf(a) | ((unsigned int)f2bf(b) << 16);
}

// ===========================================================================
// Fused convert + histogram(+rank) + W-prep + scan-state init.
// Grid-stride (2046 streaming blocks + 2 W-prep blocks) instead of r12's
// 12502 one-shot blocks (guideline 11: cap grid, stride the rest).
//  streaming blocks: x -> bf16; rank[e] = atomicAdd(&counts[dst[e]], 1)
//   (the atomic's return value IS the edge's within-bucket rank -> permute
//    needs no atomics).
//  last two blocks: repack W1/W2 into MFMA fragment order; first of them
//   also inits the lookback-scan aggregates to -1.
// ===========================================================================
__global__ __launch_bounds__(256) void convert_hist_prep(
        const float* __restrict__ x, unsigned short* __restrict__ xb, long n4,
        const int* __restrict__ dst, int* __restrict__ counts,
        int* __restrict__ rank, int E,
        const float* __restrict__ W1, const float* __restrict__ W2,
        unsigned short* __restrict__ bfW1, unsigned short* __restrict__ bfW2,
        int* __restrict__ agg, int nstream) {
    const int t = threadIdx.x;
    if (blockIdx.x >= nstream) {
        const int wsel = blockIdx.x - nstream;
        if (!wsel && t < 128) agg[t] = -1;     // lookback-scan state init
        const float* W = wsel ? W2 : W1;
        unsigned short* bfW = wsel ? bfW2 : bfW1;
#pragma unroll
        for (int it = 0; it < 8; it++) {
            const int idx = it * 256 + t;
            const int kc = idx >> 9;
            const int ct = (idx >> 6) & 7;
            const int lane = idx & 63;
            const int quad = lane >> 4;
            const int n = ct * 16 + (lane & 15);
            unsigned short frag[8];
#pragma unroll
            for (int j = 0; j < 8; j++)
                frag[j] = f2bf(W[(kc * 32 + quad * 8 + j) * FEAT + n]);
            *(uint4*)&bfW[(long)idx * 8] = *(uint4*)frag;
        }
        return;
    }
    const long gsz = (long)nstream * 256;
    for (long i = (long)blockIdx.x * 256 + t; i < n4; i += gsz) {
        const float4 v = *(const float4*)&x[i * 4];
        uint2 p;
        p.x = pack2(v.x, v.y);
        p.y = pack2(v.z, v.w);
        *(uint2*)&xb[i * 4] = p;
    }
    for (long e = (long)blockIdx.x * 256 + t; e < E; e += gsz)
        rank[e] = atomicAdd(&counts[dst[e]], 1);
}

// ===========================================================================
// FUSED scan + permute (one graph node instead of two; each node costs
// ~18-20 us of serialization — measured r12: 6 nodes, ~108 us residual).
// 512 blocks, ALL co-resident (256-thr/low-VGPR -> >=4 WG/CU capacity =
// 1024 >= 512), so intra-kernel spin is deadlock-free by the same
// co-residency argument as the r10/r12-validated lookback.
//  Phase 1 (blocks 0..NB-1): per-chunk scan + decoupled lookback over agg
//   (init -1 by convert), write offsets chunk, release-publish done++.
//  Phase 2 (all blocks): spin done==NB (t0 + barrier), acquire fence,
//   grid-stride permute: sorted_src[offsets[dst[e]] + rank[e]] = src[e].
// All published values are deterministic across graph replays, so even a
// missed cache invalidate cannot yield wrong data.
// ===========================================================================
__global__ __launch_bounds__(256) void scan_permute(
        const int* __restrict__ counts, int* __restrict__ offsets,
        int* __restrict__ agg, int* __restrict__ done,
        const int* __restrict__ src, const int* __restrict__ dst,
        const int* __restrict__ rank, int* __restrict__ sorted_src,
        int N, int E, int NB) {
    const int t = threadIdx.x;
    const int b = blockIdx.x;

    if (b < NB) {
        const int base = b * 1024 + t * 4;
        int c0 = (base + 0 < N) ? counts[base + 0] : 0;
        int c1 = (base + 1 < N) ? counts[base + 1] : 0;
        int c2 = (base + 2 < N) ? counts[base + 2] : 0;
        int c3 = (base + 3 < N) ? counts[base + 3] : 0;
        const int sum = c0 + c1 + c2 + c3;

        const int lane = t & 63, wv = t >> 6;
        int v = sum;
#pragma unroll
        for (int off = 1; off < 64; off <<= 1) {
            int n = __shfl_up(v, off);
            if (lane >= off) v += n;
        }
        __shared__ int ws[4];
        __shared__ int sbase;
        if (lane == 63) ws[wv] = v;
        __syncthreads();
        int wp = 0;
        for (int w = 0; w < wv; w++) wp += ws[w];
        const int excl = wp + v - sum;

        // publish this block's aggregate (thread 255 holds the block total)
        if (t == 255) atomicExch(&agg[b], wp + v);
        // wave 0: parallel lookback over predecessors' aggregates
        if (t < 64) {
            int s = 0;
            for (int j = t; j < b; j += 64) {
                int a;
                do { a = atomicAdd(&agg[j], 0); } while (a < 0);
                s += a;
            }
#pragma unroll
            for (int off = 32; off; off >>= 1) s += __shfl_down(s, off);
            if (t == 0) sbase = s;
        }
        __syncthreads();
        const int bb = sbase;
        if (base + 0 < N) offsets[base + 0] = bb + excl;
        if (base + 1 < N) offsets[base + 1] = bb + excl + c0;
        if (base + 2 < N) offsets[base + 2] = bb + excl + c0 + c1;
        if (base + 3 < N) offsets[base + 3] = bb + excl + c0 + c1 + c2;
        if (b == 0 && t == 0) offsets[N] = E;

        __syncthreads();                       // all offsets stores issued
        if (t == 0) { __threadfence(); atomicAdd(done, 1); }   // release
    }

    // ---- wait for every chunk of offsets, then permute ----
    if (t == 0) { while (atomicAdd(done, 0) < NB) { } }
    __syncthreads();
    __threadfence();                           // acquire
    const long gsz = (long)gridDim.x * 256;
    for (long e = (long)b * 256 + t; e < E; e += gsz)
        sorted_src[offsets[dst[e]] + rank[e]] = src[e];
}

// ===========================================================================
// FUSED gather + MFMA GEMM — the known-best compiler-scheduled structure
// (r1/r7/r12: 128 thr, __launch_bounds__(128,8), VGPR 32, ~48.3 us).
// Evidence r1/r2/r4/r7/r9: duration invariant to occupancy (28-49%), lane
// balance, and hand-pipelining -> runs at the memory system's random-access
// service ceiling (~117 MB off-L2 @ ~2.4 TB/s). r10: NT stores regress
// +15 us/dispatch — plain stores.
// ===========================================================================
template <bool RELU, bool OUT_BF16>
__global__ __launch_bounds__(128, 8) void gather_gemm(const unsigned short* __restrict__ h,
                                                      const int* __restrict__ offsets,
                                                      const int* __restrict__ sorted_src,
                                                      const unsigned short* __restrict__ bfW,
                                                      const float* __restrict__ bias,
                                                      void* __restrict__ out, int N) {
    const int t = threadIdx.x;
    const int wave = t >> 6;
    const int lane = t & 63;
    const int quad = lane >> 4;
    const int l15 = lane & 15;
    const int node = blockIdx.x * 32 + wave * 16 + l15;

    int start = 0, end = 0;
    if (node < N) { start = offsets[node]; end = offsets[node + 1]; }

    const uint4* hb = (const uint4*)h;   // 16 uint4 per 128-feat row
    float acc[4][8];
#pragma unroll
    for (int kc = 0; kc < 4; kc++)
#pragma unroll
        for (int j = 0; j < 8; j++) acc[kc][j] = 0.f;

    // ---- gather phase (lane holds edges quad*2, quad*2+1 of column l15) ----
    int e0 = start + quad * 2;
    int s0 = (e0 < end) ? sorted_src[e0] : 0;
    int s1 = (e0 + 1 < end) ? sorted_src[e0 + 1] : 0;

    for (int eb = start; eb < end; eb += 8) {
        // Prefetch next batch's indices (hides index-load latency).
        const int ne = eb + 8 + quad * 2;
        const int ns0 = (ne < end) ? sorted_src[ne] : 0;
        const int ns1 = (ne + 1 < end) ? sorted_src[ne + 1] : 0;

        const int cnt = min(8, end - eb);
#pragma unroll 8
        for (int j = 0; j < cnt; j++) {
            const int sl = (j >> 1) * 16 + l15;        // lane holding edge eb+j of column l15
            const int s = __shfl((j & 1) ? s1 : s0, sl);
            const long rb = (long)s * 16;
            uint4 u[4];
#pragma unroll
            for (int kc = 0; kc < 4; kc++) u[kc] = hb[rb + kc * 4 + quad];
#pragma unroll
            for (int kc = 0; kc < 4; kc++) {
                acc[kc][0] += bf_lo(u[kc].x); acc[kc][1] += bf_hi(u[kc].x);
                acc[kc][2] += bf_lo(u[kc].y); acc[kc][3] += bf_hi(u[kc].y);
                acc[kc][4] += bf_lo(u[kc].z); acc[kc][5] += bf_hi(u[kc].z);
                acc[kc][6] += bf_lo(u[kc].w); acc[kc][7] += bf_hi(u[kc].w);
            }
        }
        s0 = ns0; s1 = ns1;
    }

    // acc -> A fragments (register-only; layout already matches).
    short8 afrag[4];
#pragma unroll
    for (int kc = 0; kc < 4; kc++) {
        unsigned short fr[8];
#pragma unroll
        for (int j = 0; j < 8; j++) fr[j] = f2bf(acc[kc][j]);
        afrag[kc] = *(short8*)fr;
    }

    // ---- MFMA phase: B-frags straight from global (L1/L2-hot 32 KB) ----
    floatx4 cacc[8];
#pragma unroll
    for (int ct = 0; ct < 8; ct++) cacc[ct] = (floatx4){0.f, 0.f, 0.f, 0.f};
#pragma unroll
    for (int kc = 0; kc < 4; kc++) {
#pragma unroll
        for (int ct = 0; ct < 8; ct++) {
            const short8 b = *(const short8*)&bfW[((kc * 8 + ct) * 64 + lane) * 8];
            cacc[ct] = __builtin_amdgcn_mfma_f32_16x16x32_bf16(afrag[kc], b, cacc[ct], 0, 0, 0);
        }
    }

    // ---- epilogue: C/D layout col=ct*16+l15, row=quad*4+r, plain stores ----
#pragma unroll
    for (int ct = 0; ct < 8; ct++) {
        const int col = ct * 16 + l15;
        const float bv = bias[col];
#pragma unroll
        for (int r = 0; r < 4; r++) {
            const int row = blockIdx.x * 32 + wave * 16 + quad * 4 + r;
            if (row < N) {
                float v = cacc[ct][r] + bv;
                if (RELU) v = fmaxf(v, 0.f);
                if (OUT_BF16)
                    ((unsigned short*)out)[(long)row * FEAT + col] = f2bf(v);
                else
                    ((float*)out)[(long)row * FEAT + col] = v;
            }
        }
    }
}

// ===========================================================================
// Pipeline (5 graph nodes; bf16 payloads, fp32 accumulation):
//   memset counts+done
//   convert_hist_prep: x->bf16 | counts/rank | W-prep | agg init  (grid-stride)
//   scan_permute:      lookback scan -> offsets, spin, permute    (fused)
//   h1b = gather_gemm(xb, W1, b1, relu) -> bf16
//   out = gather_gemm(h1b, W2, b2)      -> fp32
// Linearity: segment_sum((hW)[src]) == (segment_sum h[src]) @ W.
// ===========================================================================
extern "C" void kernel_launch(void* const* d_in, const int* in_sizes, int n_in,
                              void* d_out, int out_size, void* d_ws, size_t ws_size,
                              hipStream_t stream) {
    const float* x  = (const float*)d_in[0];
    const int*   ei = (const int*)d_in[1];
    const float* W1 = (const float*)d_in[2];
    const float* b1 = (const float*)d_in[3];
    const float* W2 = (const float*)d_in[4];
    const float* b2 = (const float*)d_in[5];
    float* out = (float*)d_out;

    const int N = in_sizes[0] / FEAT;
    const int E = in_sizes[1] / 2;
    const int* src = ei;
    const int* dst = ei + E;

    // Workspace carve-up (~58 MB).
    unsigned short* xb   = (unsigned short*)d_ws;            // N*128 bf16
    unsigned short* h1b  = xb + (size_t)N * FEAT;            // N*128 bf16
    unsigned short* bfW1 = h1b + (size_t)N * FEAT;           // 16384
    unsigned short* bfW2 = bfW1 + 16384;                     // 16384
    int* counts    = (int*)(bfW2 + 16384);                   // [N]
    int* done      = counts + N;                             // [1]  (memset'd with counts)
    int* offsets   = done + 1;                               // [N+1]
    int* agg       = offsets + N + 1;                        // [128] scan state
    int* rank      = agg + 128;                              // [E]
    int* sorted_src = rank + E;                              // [E]

    const int NB = (N + 1023) / 1024;                        // 98 scan chunks
    const long n4 = (long)N * FEAT / 4;
    const int nstream = 2046;                                // + 2 W-prep blocks

    hipMemsetAsync(counts, 0, (size_t)(N + 1) * sizeof(int), stream);  // counts + done
    convert_hist_prep<<<nstream + 2, 256, 0, stream>>>(x, xb, n4, dst, counts, rank, E,
                                                       W1, W2, bfW1, bfW2, agg, nstream);
    scan_permute<<<512, 256, 0, stream>>>(counts, offsets, agg, done,
                                          src, dst, rank, sorted_src, N, E, NB);

    const int fused_blocks = (N + 31) / 32;

    gather_gemm<true, true><<<fused_blocks, 128, 0, stream>>>(
        xb, offsets, sorted_src, bfW1, b1, h1b, N);
    gather_gemm<false, false><<<fused_blocks, 128, 0, stream>>>(
        h1b, offsets, sorted_src, bfW2, b2, out, N);
}

// Round 14
// 277.475 us; speedup vs baseline: 1.0062x; 1.0062x over previous
//
#include <hip/hip_runtime.h>

#define FEAT 128

typedef __attribute__((ext_vector_type(8))) short short8;
typedef __attribute__((ext_vector_type(4))) float floatx4;

// bf16 helpers (manual, RNE) — finite data only.
__device__ __forceinline__ unsigned short f2bf(float f) {
    unsigned int u = __float_as_uint(f);
    u += 0x7fffu + ((u >> 16) & 1u);
    return (unsigned short)(u >> 16);
}
__device__ __forceinline__ float bf_lo(unsigned int u) { return __uint_as_float(u << 16); }
__device__ __forceinline__ float bf_hi(unsigned int u) { return __uint_as_float(u & 0xffff0000u); }
__device__ __forceinline__ unsigned int pack2(float a, float b) {
    return (unsigned int)f2bf(a) | ((unsigned int)f2bf(b) << 16);
}

// ===========================================================================
// Fused convert + histogram(+rank) + W-prep + scan-state init — EXACT r12
// form (one-shot 12502 blocks; r13's grid-stride rewrite was a hidden
// ~15 us regression, reverted).
// ===========================================================================
__global__ __launch_bounds__(256) void convert_hist_prep(
        const float* __restrict__ x, unsigned short* __restrict__ xb, long n4,
        const int* __restrict__ dst, int* __restrict__ counts,
        int* __restrict__ rank, int E,
        const float* __restrict__ W1, const float* __restrict__ W2,
        unsigned short* __restrict__ bfW1, unsigned short* __restrict__ bfW2,
        int* __restrict__ agg, int chB) {
    const int t = threadIdx.x;
    if (blockIdx.x >= chB) {
        const int wsel = blockIdx.x - chB;
        if (!wsel && t < 128) agg[t] = -1;     // lookback-scan state init
        const float* W = wsel ? W2 : W1;
        unsigned short* bfW = wsel ? bfW2 : bfW1;
#pragma unroll
        for (int it = 0; it < 8; it++) {
            const int idx = it * 256 + t;
            const int kc = idx >> 9;
            const int ct = (idx >> 6) & 7;
            const int lane = idx & 63;
            const int quad = lane >> 4;
            const int n = ct * 16 + (lane & 15);
            unsigned short frag[8];
#pragma unroll
            for (int j = 0; j < 8; j++)
                frag[j] = f2bf(W[(kc * 32 + quad * 8 + j) * FEAT + n]);
            *(uint4*)&bfW[(long)idx * 8] = *(uint4*)frag;
        }
        return;
    }
    const long i = (long)blockIdx.x * 256 + t;
    if (i < E) rank[i] = atomicAdd(&counts[dst[i]], 1);
    if (i < n4) {
        const float4 v = *(const float4*)&x[i * 4];
        uint2 p;
        p.x = pack2(v.x, v.y);
        p.y = pack2(v.z, v.w);
        *(uint2*)&xb[i * 4] = p;
    }
}

// ===========================================================================
// FUSED scan + permute, THROTTLED spins (round-14 single-variable change).
// r13's version regressed to 62.7 us: 414 foreign blocks' t0 hammering
// atomicAdd(done,0) with zero backoff serialized the one L2 atomic unit the
// scan's lookback also needs (VALUBusy 0.67%). Fix: s_sleep backoff in both
// polls (done-poll sleeps ~512 cyc between atomics — ~100x less atomic
// traffic; lookback sleeps ~128 cyc on miss). 512 blocks, all co-resident
// (256 thr, low VGPR), spin deadlock-free.
// ===========================================================================
__global__ __launch_bounds__(256) void scan_permute(
        const int* __restrict__ counts, int* __restrict__ offsets,
        int* __restrict__ agg, int* __restrict__ done,
        const int* __restrict__ src, const int* __restrict__ dst,
        const int* __restrict__ rank, int* __restrict__ sorted_src,
        int N, int E, int NB) {
    const int t = threadIdx.x;
    const int b = blockIdx.x;

    if (b < NB) {
        const int base = b * 1024 + t * 4;
        int c0 = (base + 0 < N) ? counts[base + 0] : 0;
        int c1 = (base + 1 < N) ? counts[base + 1] : 0;
        int c2 = (base + 2 < N) ? counts[base + 2] : 0;
        int c3 = (base + 3 < N) ? counts[base + 3] : 0;
        const int sum = c0 + c1 + c2 + c3;

        const int lane = t & 63, wv = t >> 6;
        int v = sum;
#pragma unroll
        for (int off = 1; off < 64; off <<= 1) {
            int n = __shfl_up(v, off);
            if (lane >= off) v += n;
        }
        __shared__ int ws[4];
        __shared__ int sbase;
        if (lane == 63) ws[wv] = v;
        __syncthreads();
        int wp = 0;
        for (int w = 0; w < wv; w++) wp += ws[w];
        const int excl = wp + v - sum;

        // publish this block's aggregate (thread 255 holds the block total)
        if (t == 255) atomicExch(&agg[b], wp + v);
        // wave 0: parallel lookback with backoff
        if (t < 64) {
            int s = 0;
            for (int j = t; j < b; j += 64) {
                int a = atomicAdd(&agg[j], 0);
                while (a < 0) { __builtin_amdgcn_s_sleep(2); a = atomicAdd(&agg[j], 0); }
                s += a;
            }
#pragma unroll
            for (int off = 32; off; off >>= 1) s += __shfl_down(s, off);
            if (t == 0) sbase = s;
        }
        __syncthreads();
        const int bb = sbase;
        if (base + 0 < N) offsets[base + 0] = bb + excl;
        if (base + 1 < N) offsets[base + 1] = bb + excl + c0;
        if (base + 2 < N) offsets[base + 2] = bb + excl + c0 + c1;
        if (base + 3 < N) offsets[base + 3] = bb + excl + c0 + c1 + c2;
        if (b == 0 && t == 0) offsets[N] = E;

        __syncthreads();                       // all offsets stores issued
        if (t == 0) { __threadfence(); atomicAdd(done, 1); }   // release
    }

    // ---- wait for every chunk of offsets (throttled), then permute ----
    if (t == 0) {
        while (atomicAdd(done, 0) < NB) __builtin_amdgcn_s_sleep(8);
    }
    __syncthreads();
    __threadfence();                           // acquire
    const long gsz = (long)gridDim.x * 256;
    for (long e = (long)b * 256 + t; e < E; e += gsz)
        sorted_src[offsets[dst[e]] + rank[e]] = src[e];
}

// ===========================================================================
// FUSED gather + MFMA GEMM — the known-best compiler-scheduled structure
// (r1/r7/r12: 128 thr, __launch_bounds__(128,8), VGPR 32, ~48.3 us).
// Evidence r1/r2/r4/r7/r9: duration invariant to occupancy (28-49%), lane
// balance, and hand-pipelining -> runs at the memory system's random-access
// service ceiling. r10: NT stores regress +15 us/dispatch — plain stores.
// UNTOUCHED since r12.
// ===========================================================================
template <bool RELU, bool OUT_BF16>
__global__ __launch_bounds__(128, 8) void gather_gemm(const unsigned short* __restrict__ h,
                                                      const int* __restrict__ offsets,
                                                      const int* __restrict__ sorted_src,
                                                      const unsigned short* __restrict__ bfW,
                                                      const float* __restrict__ bias,
                                                      void* __restrict__ out, int N) {
    const int t = threadIdx.x;
    const int wave = t >> 6;
    const int lane = t & 63;
    const int quad = lane >> 4;
    const int l15 = lane & 15;
    const int node = blockIdx.x * 32 + wave * 16 + l15;

    int start = 0, end = 0;
    if (node < N) { start = offsets[node]; end = offsets[node + 1]; }

    const uint4* hb = (const uint4*)h;   // 16 uint4 per 128-feat row
    float acc[4][8];
#pragma unroll
    for (int kc = 0; kc < 4; kc++)
#pragma unroll
        for (int j = 0; j < 8; j++) acc[kc][j] = 0.f;

    // ---- gather phase (lane holds edges quad*2, quad*2+1 of column l15) ----
    int e0 = start + quad * 2;
    int s0 = (e0 < end) ? sorted_src[e0] : 0;
    int s1 = (e0 + 1 < end) ? sorted_src[e0 + 1] : 0;

    for (int eb = start; eb < end; eb += 8) {
        // Prefetch next batch's indices (hides index-load latency).
        const int ne = eb + 8 + quad * 2;
        const int ns0 = (ne < end) ? sorted_src[ne] : 0;
        const int ns1 = (ne + 1 < end) ? sorted_src[ne + 1] : 0;

        const int cnt = min(8, end - eb);
#pragma unroll 8
        for (int j = 0; j < cnt; j++) {
            const int sl = (j >> 1) * 16 + l15;        // lane holding edge eb+j of column l15
            const int s = __shfl((j & 1) ? s1 : s0, sl);
            const long rb = (long)s * 16;
            uint4 u[4];
#pragma unroll
            for (int kc = 0; kc < 4; kc++) u[kc] = hb[rb + kc * 4 + quad];
#pragma unroll
            for (int kc = 0; kc < 4; kc++) {
                acc[kc][0] += bf_lo(u[kc].x); acc[kc][1] += bf_hi(u[kc].x);
                acc[kc][2] += bf_lo(u[kc].y); acc[kc][3] += bf_hi(u[kc].y);
                acc[kc][4] += bf_lo(u[kc].z); acc[kc][5] += bf_hi(u[kc].z);
                acc[kc][6] += bf_lo(u[kc].w); acc[kc][7] += bf_hi(u[kc].w);
            }
        }
        s0 = ns0; s1 = ns1;
    }

    // acc -> A fragments (register-only; layout already matches).
    short8 afrag[4];
#pragma unroll
    for (int kc = 0; kc < 4; kc++) {
        unsigned short fr[8];
#pragma unroll
        for (int j = 0; j < 8; j++) fr[j] = f2bf(acc[kc][j]);
        afrag[kc] = *(short8*)fr;
    }

    // ---- MFMA phase: B-frags straight from global (L1/L2-hot 32 KB) ----
    floatx4 cacc[8];
#pragma unroll
    for (int ct = 0; ct < 8; ct++) cacc[ct] = (floatx4){0.f, 0.f, 0.f, 0.f};
#pragma unroll
    for (int kc = 0; kc < 4; kc++) {
#pragma unroll
        for (int ct = 0; ct < 8; ct++) {
            const short8 b = *(const short8*)&bfW[((kc * 8 + ct) * 64 + lane) * 8];
            cacc[ct] = __builtin_amdgcn_mfma_f32_16x16x32_bf16(afrag[kc], b, cacc[ct], 0, 0, 0);
        }
    }

    // ---- epilogue: C/D layout col=ct*16+l15, row=quad*4+r, plain stores ----
#pragma unroll
    for (int ct = 0; ct < 8; ct++) {
        const int col = ct * 16 + l15;
        const float bv = bias[col];
#pragma unroll
        for (int r = 0; r < 4; r++) {
            const int row = blockIdx.x * 32 + wave * 16 + quad * 4 + r;
            if (row < N) {
                float v = cacc[ct][r] + bv;
                if (RELU) v = fmaxf(v, 0.f);
                if (OUT_BF16)
                    ((unsigned short*)out)[(long)row * FEAT + col] = f2bf(v);
                else
                    ((float*)out)[(long)row * FEAT + col] = v;
            }
        }
    }
}

// ===========================================================================
// Pipeline (5 graph nodes; bf16 payloads, fp32 accumulation):
//   memset counts+done
//   convert_hist_prep: x->bf16 | counts/rank | W-prep | agg init  (r12 form)
//   scan_permute:      lookback scan -> offsets, throttled spin, permute
//   h1b = gather_gemm(xb, W1, b1, relu) -> bf16
//   out = gather_gemm(h1b, W2, b2)      -> fp32
// Linearity: segment_sum((hW)[src]) == (segment_sum h[src]) @ W.
// ===========================================================================
extern "C" void kernel_launch(void* const* d_in, const int* in_sizes, int n_in,
                              void* d_out, int out_size, void* d_ws, size_t ws_size,
                              hipStream_t stream) {
    const float* x  = (const float*)d_in[0];
    const int*   ei = (const int*)d_in[1];
    const float* W1 = (const float*)d_in[2];
    const float* b1 = (const float*)d_in[3];
    const float* W2 = (const float*)d_in[4];
    const float* b2 = (const float*)d_in[5];
    float* out = (float*)d_out;

    const int N = in_sizes[0] / FEAT;
    const int E = in_sizes[1] / 2;
    const int* src = ei;
    const int* dst = ei + E;

    // Workspace carve-up (~58 MB).
    unsigned short* xb   = (unsigned short*)d_ws;            // N*128 bf16
    unsigned short* h1b  = xb + (size_t)N * FEAT;            // N*128 bf16
    unsigned short* bfW1 = h1b + (size_t)N * FEAT;           // 16384
    unsigned short* bfW2 = bfW1 + 16384;                     // 16384
    int* counts    = (int*)(bfW2 + 16384);                   // [N]
    int* done      = counts + N;                             // [1]  (memset'd with counts)
    int* offsets   = done + 1;                               // [N+1]
    int* agg       = offsets + N + 1;                        // [128] scan state
    int* rank      = agg + 128;                              // [E]
    int* sorted_src = rank + E;                              // [E]

    const int NB = (N + 1023) / 1024;                        // 98 scan chunks
    const long n4 = (long)N * FEAT / 4;
    const int chB = (int)((n4 + 255) / 256);

    hipMemsetAsync(counts, 0, (size_t)(N + 1) * sizeof(int), stream);  // counts + done
    convert_hist_prep<<<chB + 2, 256, 0, stream>>>(x, xb, n4, dst, counts, rank, E,
                                                   W1, W2, bfW1, bfW2, agg, chB);
    scan_permute<<<512, 256, 0, stream>>>(counts, offsets, agg, done,
                                          src, dst, rank, sorted_src, N, E, NB);

    const int fused_blocks = (N + 31) / 32;

    gather_gemm<true, true><<<fused_blocks, 128, 0, stream>>>(
        xb, offsets, sorted_src, bfW1, b1, h1b, N);
    gather_gemm<false, false><<<fused_blocks, 128, 0, stream>>>(
        h1b, offsets, sorted_src, bfW2, b2, out, N);
}

// Round 15
// 237.959 us; speedup vs baseline: 1.1732x; 1.1661x over previous
//
#include <hip/hip_runtime.h>

#define FEAT 128

typedef __attribute__((ext_vector_type(8))) short short8;
typedef __attribute__((ext_vector_type(4))) float floatx4;

// bf16 helpers (manual, RNE) — finite data only.
__device__ __forceinline__ unsigned short f2bf(float f) {
    unsigned int u = __float_as_uint(f);
    u += 0x7fffu + ((u >> 16) & 1u);
    return (unsigned short)(u >> 16);
}
__device__ __forceinline__ float bf_lo(unsigned int u) { return __uint_as_float(u << 16); }
__device__ __forceinline__ float bf_hi(unsigned int u) { return __uint_as_float(u & 0xffff0000u); }
__device__ __forceinline__ unsigned int pack2(float a, float b) {
    return (unsigned int)f2bf(a) | ((unsigned int)f2bf(b) << 16);
}

// ===========================================================================
// Fused convert + histogram(+rank) + W-prep + scan-state init (r12 form —
// verified 239.2 us total; r13's grid-stride variant regressed, reverted):
//  blocks [0, chB): stream x -> bf16; rank[e] = atomicAdd(counts[dst[e]],1)
//   (the atomic's return value IS the edge's within-bucket rank -> permute
//    is atomic-free: pos = offsets[dst] + rank).
//  blocks chB, chB+1: repack W1/W2 into MFMA fragment order; block chB also
//   initializes the lookback-scan aggregates to -1.
// ===========================================================================
__global__ __launch_bounds__(256) void convert_hist_prep(
        const float* __restrict__ x, unsigned short* __restrict__ xb, long n4,
        const int* __restrict__ dst, int* __restrict__ counts,
        int* __restrict__ rank, int E,
        const float* __restrict__ W1, const float* __restrict__ W2,
        unsigned short* __restrict__ bfW1, unsigned short* __restrict__ bfW2,
        int* __restrict__ agg, int chB) {
    const int t = threadIdx.x;
    if (blockIdx.x >= chB) {
        const int wsel = blockIdx.x - chB;
        if (!wsel && t < 128) agg[t] = -1;     // lookback-scan state init
        const float* W = wsel ? W2 : W1;
        unsigned short* bfW = wsel ? bfW2 : bfW1;
#pragma unroll
        for (int it = 0; it < 8; it++) {
            const int idx = it * 256 + t;
            const int kc = idx >> 9;
            const int ct = (idx >> 6) & 7;
            const int lane = idx & 63;
            const int quad = lane >> 4;
            const int n = ct * 16 + (lane & 15);
            unsigned short frag[8];
#pragma unroll
            for (int j = 0; j < 8; j++)
                frag[j] = f2bf(W[(kc * 32 + quad * 8 + j) * FEAT + n]);
            *(uint4*)&bfW[(long)idx * 8] = *(uint4*)frag;
        }
        return;
    }
    const long i = (long)blockIdx.x * 256 + t;
    if (i < E) rank[i] = atomicAdd(&counts[dst[i]], 1);
    if (i < n4) {
        const float4 v = *(const float4*)&x[i * 4];
        uint2 p;
        p.x = pack2(v.x, v.y);
        p.y = pack2(v.z, v.w);
        *(uint2*)&xb[i * 4] = p;
    }
}

// ===========================================================================
// Single-kernel exclusive scan via decoupled lookback (aggregates-only):
// 98 blocks x (256 thr x 4 elems). Each block publishes its local total
// with a device-scope atomicExch (agg init -1 by convert kernel), then wave
// 0 spin-reads ALL predecessor aggregates in parallel (98 blocks <= 256 CUs
// so all resident, spin-safe).
// NOTE r13/r14: fusing the permute into this kernel regresses to ~62 us —
// the fused form serializes behind the sorted_src scatter's cross-XCD
// write-amplification (20.7 MB HBM writes for 3 MB of data). Keep separate.
// ===========================================================================
__global__ __launch_bounds__(256) void scan_fused(const int* __restrict__ counts,
                                                  int* __restrict__ offsets,
                                                  int* __restrict__ agg,
                                                  int N, int E) {
    const int t = threadIdx.x;
    const int b = blockIdx.x;
    const int base = b * 1024 + t * 4;
    int c0 = (base + 0 < N) ? counts[base + 0] : 0;
    int c1 = (base + 1 < N) ? counts[base + 1] : 0;
    int c2 = (base + 2 < N) ? counts[base + 2] : 0;
    int c3 = (base + 3 < N) ? counts[base + 3] : 0;
    const int sum = c0 + c1 + c2 + c3;

    const int lane = t & 63, wv = t >> 6;
    int v = sum;
#pragma unroll
    for (int off = 1; off < 64; off <<= 1) {
        int n = __shfl_up(v, off);
        if (lane >= off) v += n;
    }
    __shared__ int ws[4];
    __shared__ int sbase;
    if (lane == 63) ws[wv] = v;
    __syncthreads();
    int wp = 0;
    for (int w = 0; w < wv; w++) wp += ws[w];
    const int excl = wp + v - sum;

    // publish this block's aggregate (thread 255 holds the block total)
    if (t == 255) atomicExch(&agg[b], wp + v);
    // wave 0: parallel lookback over predecessors' aggregates
    if (t < 64) {
        int s = 0;
        for (int j = t; j < b; j += 64) {
            int a;
            do { a = atomicAdd(&agg[j], 0); } while (a < 0);
            s += a;
        }
#pragma unroll
        for (int off = 32; off; off >>= 1) s += __shfl_down(s, off);
        if (t == 0) sbase = s;
    }
    __syncthreads();
    const int bb = sbase;
    if (base + 0 < N) offsets[base + 0] = bb + excl;
    if (base + 1 < N) offsets[base + 1] = bb + excl + c0;
    if (base + 2 < N) offsets[base + 2] = bb + excl + c0 + c1;
    if (base + 3 < N) offsets[base + 3] = bb + excl + c0 + c1 + c2;
    if (b == 0 && t == 0) offsets[N] = E;
}

// ===========================================================================
// Atomic-free permute: pos = offsets[dst[e]] + rank[e].
// ===========================================================================
__global__ __launch_bounds__(256) void permute_kernel(const int* __restrict__ src,
                                                      const int* __restrict__ dst,
                                                      const int* __restrict__ rank,
                                                      const int* __restrict__ offsets,
                                                      int* __restrict__ sorted_src, int E) {
    const int e = blockIdx.x * 256 + threadIdx.x;
    if (e < E) {
        const int pos = offsets[dst[e]] + rank[e];
        sorted_src[pos] = src[e];
    }
}

// ===========================================================================
// FUSED gather + MFMA GEMM — the known-best compiler-scheduled structure
// (r1/r7/r12: 128 thr, __launch_bounds__(128,8), VGPR 32, ~48.3 us).
// Ceiling evidence (5 independent falsifications):
//   r1/r2: +VGPR headroom / paired loads -> no change (compiler re-serializes)
//   r4:    occupancy 49%->28% at pinned waves/EU -> no change
//   r7:    degree-balanced waves (zero edge-loop divergence) -> no change
//   r9:    hand-written counted-vmcnt asm pipeline -> WORSE (75 us)
//   r10:   NT epilogue stores -> WORSE (+15 us/dispatch)
// -> the gather runs at the memory system's random-64B-access service
// ceiling (~117 MB off-L2 per dispatch @ ~2.4 TB/s). fp8 payload compression
// is numerically excluded (bf16 already at the 0.125 absmax budget).
// ===========================================================================
template <bool RELU, bool OUT_BF16>
__global__ __launch_bounds__(128, 8) void gather_gemm(const unsigned short* __restrict__ h,
                                                      const int* __restrict__ offsets,
                                                      const int* __restrict__ sorted_src,
                                                      const unsigned short* __restrict__ bfW,
                                                      const float* __restrict__ bias,
                                                      void* __restrict__ out, int N) {
    const int t = threadIdx.x;
    const int wave = t >> 6;
    const int lane = t & 63;
    const int quad = lane >> 4;
    const int l15 = lane & 15;
    const int node = blockIdx.x * 32 + wave * 16 + l15;

    int start = 0, end = 0;
    if (node < N) { start = offsets[node]; end = offsets[node + 1]; }

    const uint4* hb = (const uint4*)h;   // 16 uint4 per 128-feat row
    float acc[4][8];
#pragma unroll
    for (int kc = 0; kc < 4; kc++)
#pragma unroll
        for (int j = 0; j < 8; j++) acc[kc][j] = 0.f;

    // ---- gather phase (lane holds edges quad*2, quad*2+1 of column l15) ----
    int e0 = start + quad * 2;
    int s0 = (e0 < end) ? sorted_src[e0] : 0;
    int s1 = (e0 + 1 < end) ? sorted_src[e0 + 1] : 0;

    for (int eb = start; eb < end; eb += 8) {
        // Prefetch next batch's indices (hides index-load latency).
        const int ne = eb + 8 + quad * 2;
        const int ns0 = (ne < end) ? sorted_src[ne] : 0;
        const int ns1 = (ne + 1 < end) ? sorted_src[ne + 1] : 0;

        const int cnt = min(8, end - eb);
#pragma unroll 8
        for (int j = 0; j < cnt; j++) {
            const int sl = (j >> 1) * 16 + l15;        // lane holding edge eb+j of column l15
            const int s = __shfl((j & 1) ? s1 : s0, sl);
            const long rb = (long)s * 16;
            uint4 u[4];
#pragma unroll
            for (int kc = 0; kc < 4; kc++) u[kc] = hb[rb + kc * 4 + quad];
#pragma unroll
            for (int kc = 0; kc < 4; kc++) {
                acc[kc][0] += bf_lo(u[kc].x); acc[kc][1] += bf_hi(u[kc].x);
                acc[kc][2] += bf_lo(u[kc].y); acc[kc][3] += bf_hi(u[kc].y);
                acc[kc][4] += bf_lo(u[kc].z); acc[kc][5] += bf_hi(u[kc].z);
                acc[kc][6] += bf_lo(u[kc].w); acc[kc][7] += bf_hi(u[kc].w);
            }
        }
        s0 = ns0; s1 = ns1;
    }

    // acc -> A fragments (register-only; layout already matches).
    short8 afrag[4];
#pragma unroll
    for (int kc = 0; kc < 4; kc++) {
        unsigned short fr[8];
#pragma unroll
        for (int j = 0; j < 8; j++) fr[j] = f2bf(acc[kc][j]);
        afrag[kc] = *(short8*)fr;
    }

    // ---- MFMA phase: B-frags straight from global (L1/L2-hot 32 KB) ----
    floatx4 cacc[8];
#pragma unroll
    for (int ct = 0; ct < 8; ct++) cacc[ct] = (floatx4){0.f, 0.f, 0.f, 0.f};
#pragma unroll
    for (int kc = 0; kc < 4; kc++) {
#pragma unroll
        for (int ct = 0; ct < 8; ct++) {
            const short8 b = *(const short8*)&bfW[((kc * 8 + ct) * 64 + lane) * 8];
            cacc[ct] = __builtin_amdgcn_mfma_f32_16x16x32_bf16(afrag[kc], b, cacc[ct], 0, 0, 0);
        }
    }

    // ---- epilogue: C/D layout col=ct*16+l15, row=quad*4+r, plain stores ----
#pragma unroll
    for (int ct = 0; ct < 8; ct++) {
        const int col = ct * 16 + l15;
        const float bv = bias[col];
#pragma unroll
        for (int r = 0; r < 4; r++) {
            const int row = blockIdx.x * 32 + wave * 16 + quad * 4 + r;
            if (row < N) {
                float v = cacc[ct][r] + bv;
                if (RELU) v = fmaxf(v, 0.f);
                if (OUT_BF16)
                    ((unsigned short*)out)[(long)row * FEAT + col] = f2bf(v);
                else
                    ((float*)out)[(long)row * FEAT + col] = v;
            }
        }
    }
}

// ===========================================================================
// Pipeline (6 graph nodes; bf16 payloads, fp32 accumulation) — r12 verified
// best (239.2 us, absmax 0.125):
//   memset counts
//   convert_hist_prep: x->bf16 | counts/rank | W-prep | agg init
//   scan_fused:        decoupled-lookback exclusive scan -> offsets
//   permute:           atomic-free edge placement
//   h1b = gather_gemm(xb, W1, b1, relu) -> bf16
//   out = gather_gemm(h1b, W2, b2)      -> fp32
// Linearity: segment_sum((hW)[src]) == (segment_sum h[src]) @ W.
// ===========================================================================
extern "C" void kernel_launch(void* const* d_in, const int* in_sizes, int n_in,
                              void* d_out, int out_size, void* d_ws, size_t ws_size,
                              hipStream_t stream) {
    const float* x  = (const float*)d_in[0];
    const int*   ei = (const int*)d_in[1];
    const float* W1 = (const float*)d_in[2];
    const float* b1 = (const float*)d_in[3];
    const float* W2 = (const float*)d_in[4];
    const float* b2 = (const float*)d_in[5];
    float* out = (float*)d_out;

    const int N = in_sizes[0] / FEAT;
    const int E = in_sizes[1] / 2;
    const int* src = ei;
    const int* dst = ei + E;

    // Workspace carve-up (~58 MB).
    unsigned short* xb   = (unsigned short*)d_ws;            // N*128 bf16
    unsigned short* h1b  = xb + (size_t)N * FEAT;            // N*128 bf16
    unsigned short* bfW1 = h1b + (size_t)N * FEAT;           // 16384
    unsigned short* bfW2 = bfW1 + 16384;                     // 16384
    int* counts    = (int*)(bfW2 + 16384);                   // [N]
    int* offsets   = counts + N;                             // [N+1]
    int* agg       = offsets + N + 1;                        // [128] scan state
    int* rank      = agg + 128;                              // [E]
    int* sorted_src = rank + E;                              // [E]

    const int eb = (E + 255) / 256;
    const int NB = (N + 1023) / 1024;
    const long n4 = (long)N * FEAT / 4;
    const int chB = (int)((n4 + 255) / 256);

    hipMemsetAsync(counts, 0, (size_t)N * sizeof(int), stream);
    convert_hist_prep<<<chB + 2, 256, 0, stream>>>(x, xb, n4, dst, counts, rank, E,
                                                   W1, W2, bfW1, bfW2, agg, chB);
    scan_fused<<<NB, 256, 0, stream>>>(counts, offsets, agg, N, E);
    permute_kernel<<<eb, 256, 0, stream>>>(src, dst, rank, offsets, sorted_src, E);

    const int fused_blocks = (N + 31) / 32;

    gather_gemm<true, true><<<fused_blocks, 128, 0, stream>>>(
        xb, offsets, sorted_src, bfW1, b1, h1b, N);
    gather_gemm<false, false><<<fused_blocks, 128, 0, stream>>>(
        h1b, offsets, sorted_src, bfW2, b2, out, N);
}